// Round 4
// baseline (547.973 us; speedup 1.0000x reference)
//
#include <hip/hip_runtime.h>

// Shapes: B=2, L=2048, D_MODEL=1024, H=16, D_K=64
// Pipeline:
//  0) pack_mask: mask int32 [B][L][L] -> bit-packed u32 [B][L][L/32].
//  1) gemm_proj<0/1>: Q/K = x @ W^T (f32 in, f16 out, head-major [bh][l][64]).
//     Q pre-scaled by 1/16 = (1/sqrt(64)) * (1/2)  [entmax z = scores/2].
//  2) gemm_proj<2>: V projection, epilogue writes Vt [bh][64][l] directly.
//  3) attn_entmax: block = 16 queries x 2048 keys, 8 waves.
//     Phase 1: swapped QK^T per 256-key wave slice -> mask -> f16 -> swizzled LDS S[16][2048].
//     Phase 2: wave w owns queries {2w,2w+1}: WAVE-LOCAL entmax (zmax + 6 Newton
//              iters in packed f16 + 2 exact f32 support refines); P in place.
//              Zero barriers in this phase (waves independent -> latency hiding).
//     Phase 3: PV mfma (B-frags from LDS), cross-wave O reduce (Ored overlays S).
//  4) gemm_proj<3>: out = AO @ Wo^T -> f32 d_out.

typedef _Float16 f16;
typedef __attribute__((ext_vector_type(8))) _Float16 f16x8;
typedef __attribute__((ext_vector_type(4))) _Float16 f16x4;
typedef __attribute__((ext_vector_type(2))) _Float16 f16x2;
typedef __attribute__((ext_vector_type(4))) float f32x4;
typedef unsigned int u32;

static __device__ __forceinline__ f16x2 max2(f16x2 a, f16x2 b) {
    f16x2 r;
    r.x = a.x > b.x ? a.x : b.x;
    r.y = a.y > b.y ? a.y : b.y;
    return r;
}

// ---------------------------------------------------------------------------
// mask [2][2048][2048] int -> bits [2][2048][64] u32
// ---------------------------------------------------------------------------
__global__ __launch_bounds__(256)
void pack_mask(const int* __restrict__ mask, u32* __restrict__ bits)
{
    int idx = blockIdx.x * 256 + threadIdx.x;        // 0..262143
    const int4* p = (const int4*)&mask[(size_t)idx * 32];
    u32 v = 0;
#pragma unroll
    for (int i = 0; i < 8; i++) {
        int4 m = p[i];
        if (m.x != 0) v |= 1u << (i * 4 + 0);
        if (m.y != 0) v |= 1u << (i * 4 + 1);
        if (m.z != 0) v |= 1u << (i * 4 + 2);
        if (m.w != 0) v |= 1u << (i * 4 + 3);
    }
    bits[idx] = v;
}

// ---------------------------------------------------------------------------
// GEMM: C[M=4096, N=1024] = A[M,1024] * W[N,K=1024]^T
// MODE 0: Q (f16, *1/16, head-major)  1: K  2: V->Vt [bh][64][l]  3: OUT f32
// ---------------------------------------------------------------------------
template <int MODE>
__global__ __launch_bounds__(512)
void gemm_proj(const void* __restrict__ Ap, const float* __restrict__ Wp,
               void* __restrict__ Cp)
{
    __shared__ __align__(16) f16 As[128 * 40];
    __shared__ __align__(16) f16 Bs[128 * 40];

    const int tid = threadIdx.x;
    const int mBase = blockIdx.x * 128;
    const int nBase = blockIdx.y * 128;

    const int lane = tid & 63, w = tid >> 6;
    const int g = lane >> 4, c = lane & 15;
    const int wm = w >> 1, wn = w & 1;

    const int sr = tid >> 2;
    const int sq = tid & 3;

    f32x4 acc[2][4];
    const f32x4 vzero = {0.f, 0.f, 0.f, 0.f};
#pragma unroll
    for (int i = 0; i < 2; i++)
#pragma unroll
        for (int j = 0; j < 4; j++) acc[i][j] = vzero;

    for (int k0 = 0; k0 < 1024; k0 += 32) {
        __syncthreads();
        {
            f16x8 av;
            if constexpr (MODE == 3) {
                const f16* A = (const f16*)Ap;
                av = *(const f16x8*)&A[(size_t)(mBase + sr) * 1024 + k0 + sq * 8];
            } else {
                const float* A = (const float*)Ap;
                const float4* p = (const float4*)&A[(size_t)(mBase + sr) * 1024 + k0 + sq * 8];
                float4 x0 = p[0], x1 = p[1];
                av[0] = (f16)x0.x; av[1] = (f16)x0.y; av[2] = (f16)x0.z; av[3] = (f16)x0.w;
                av[4] = (f16)x1.x; av[5] = (f16)x1.y; av[6] = (f16)x1.z; av[7] = (f16)x1.w;
            }
            *(f16x8*)&As[sr * 40 + sq * 8] = av;

            const float4* pw = (const float4*)&Wp[(size_t)(nBase + sr) * 1024 + k0 + sq * 8];
            float4 w0 = pw[0], w1 = pw[1];
            f16x8 bv;
            bv[0] = (f16)w0.x; bv[1] = (f16)w0.y; bv[2] = (f16)w0.z; bv[3] = (f16)w0.w;
            bv[4] = (f16)w1.x; bv[5] = (f16)w1.y; bv[6] = (f16)w1.z; bv[7] = (f16)w1.w;
            *(f16x8*)&Bs[sr * 40 + sq * 8] = bv;
        }
        __syncthreads();

        f16x8 af[2], bf[4];
#pragma unroll
        for (int mt = 0; mt < 2; mt++)
            af[mt] = *(const f16x8*)&As[(wm * 32 + mt * 16 + c) * 40 + g * 8];
#pragma unroll
        for (int nt = 0; nt < 4; nt++)
            bf[nt] = *(const f16x8*)&Bs[(wn * 64 + nt * 16 + c) * 40 + g * 8];
#pragma unroll
        for (int mt = 0; mt < 2; mt++)
#pragma unroll
            for (int nt = 0; nt < 4; nt++)
                acc[mt][nt] = __builtin_amdgcn_mfma_f32_16x16x32_f16(af[mt], bf[nt], acc[mt][nt], 0, 0, 0);
    }

#pragma unroll
    for (int mt = 0; mt < 2; mt++)
#pragma unroll
        for (int nt = 0; nt < 4; nt++) {
            int row0 = mBase + wm * 32 + mt * 16 + g * 4;
            int col = nBase + wn * 64 + nt * 16 + c;
            if constexpr (MODE == 3) {
#pragma unroll
                for (int r = 0; r < 4; r++)
                    ((float*)Cp)[(size_t)(row0 + r) * 1024 + col] = acc[mt][nt][r];
            } else if constexpr (MODE == 2) {
                int b = row0 >> 11, l0 = row0 & 2047;
                int h = col >> 6, dk = col & 63;
                f16x4 pv;
#pragma unroll
                for (int r = 0; r < 4; r++) pv[r] = (f16)acc[mt][nt][r];
                *(f16x4*)&((f16*)Cp)[((size_t)(b * 16 + h) * 64 + dk) * 2048 + l0] = pv;
            } else {
#pragma unroll
                for (int r = 0; r < 4; r++) {
                    int row = row0 + r;
                    float v = acc[mt][nt][r];
                    if constexpr (MODE == 0) v *= 0.0625f;
                    int b = row >> 11, l = row & 2047;
                    int h = col >> 6, dk = col & 63;
                    ((f16*)Cp)[((size_t)(b * 16 + h) * 2048 + l) * 64 + dk] = (f16)v;
                }
            }
        }
}

// ---------------------------------------------------------------------------
// Attention + exact 1.5-entmax, wave-local solver.
// ---------------------------------------------------------------------------
__global__ __launch_bounds__(512, 4)
void attn_entmax(const f16* __restrict__ Q, const f16* __restrict__ Kh,
                 const f16* __restrict__ Vt, const u32* __restrict__ mbits,
                 f16* __restrict__ AO)
{
    // 64 KB: phase 1/2/3a: S/P f16[16][2048], chunk-XOR swizzled; phase 3b: Ored f32
    __shared__ __align__(16) char LB[65536];

    const int tid = threadIdx.x;
    const int w = tid >> 6, lane = tid & 63;
    const int g = lane >> 4, c = lane & 15;
    const int bh = blockIdx.y, b = bh >> 4, h = bh & 15;
    const int qb = blockIdx.x * 16;
    const int kbase = w * 256;
    const int swc = (c & 7) << 4;

    // ---- Phase 1: scores -> mask -> f16 -> swizzled LDS ----
    const f16* qp = &Q[(size_t)(bh * 2048 + qb + c) * 64 + g * 8];
    f16x8 bq0 = *(const f16x8*)qp;
    f16x8 bq1 = *(const f16x8*)(qp + 32);

    const uint4* mp = (const uint4*)&mbits[(size_t)(b * 2048 + qb + c) * 64 + w * 8];
    uint4 mA = mp[0], mB = mp[1];
    u32 mb[8] = {mA.x, mA.y, mA.z, mA.w, mB.x, mB.y, mB.z, mB.w};

    const f32x4 vz = {0.f, 0.f, 0.f, 0.f};
#pragma unroll
    for (int t = 0; t < 16; t++) {
        const f16* kp = &Kh[(size_t)(bh * 2048 + kbase + t * 16 + c) * 64 + g * 8];
        f16x8 ka0 = *(const f16x8*)kp;
        f16x8 ka1 = *(const f16x8*)(kp + 32);
        f32x4 z = __builtin_amdgcn_mfma_f32_16x16x32_f16(ka0, bq0, vz, 0, 0, 0);
        z = __builtin_amdgcn_mfma_f32_16x16x32_f16(ka1, bq1, z, 0, 0, 0);
        u32 b4 = mb[t >> 1] >> ((t & 1) * 16 + g * 4);
#pragma unroll
        for (int r = 0; r < 4; r++)
            if (!((b4 >> r) & 1)) z[r] = -30000.f;
        f16x4 pv;
#pragma unroll
        for (int r = 0; r < 4; r++) pv[r] = (f16)z[r];
        int byte = c * 4096 + ((((kbase + t * 16 + g * 4) * 2)) ^ swc);
        *(f16x4*)&LB[byte] = pv;
    }
    __syncthreads();

    // ---- Phase 2: wave-local entmax for queries {2w, 2w+1} ----
    f16x2 zq[2][16];
#pragma unroll
    for (int qi = 0; qi < 2; qi++) {
        const int q = 2 * w + qi;
        const int base = q * 4096, sw = (q & 7) << 4;
#pragma unroll
        for (int i = 0; i < 4; i++) {
            union { f16x8 v; f16x2 h[4]; } u;
            u.v = *(const f16x8*)&LB[base + (((lane + 64 * i) << 4) ^ sw)];
#pragma unroll
            for (int j = 0; j < 4; j++) zq[qi][i * 4 + j] = u.h[j];
        }
    }

    f16x2 zero2; zero2.x = (f16)0.f; zero2.y = (f16)0.f;
    float tau[2], zmx[2];
#pragma unroll
    for (int qi = 0; qi < 2; qi++) {
        f16x2 m = zq[qi][0];
#pragma unroll
        for (int i = 1; i < 16; i++) m = max2(m, zq[qi][i]);
        float mm = fmaxf((float)m.x, (float)m.y);
#pragma unroll
        for (int off = 1; off <= 32; off <<= 1) mm = fmaxf(mm, __shfl_xor(mm, off));
        zmx[qi] = mm;
        tau[qi] = mm - 1.0f;
    }

    // Newton from below (packed f16 scans, intra-wave shuffle reduce)
#pragma unroll 1
    for (int it = 0; it < 6; ++it) {
        float s1a[2], s2a[2];
#pragma unroll
        for (int qi = 0; qi < 2; qi++) {
            f16 tn = (f16)tau[qi];
            f16x2 tv; tv.x = tn; tv.y = tn;
            f16x2 s1p = zero2, s2p = zero2;
#pragma unroll
            for (int i = 0; i < 16; i++) {
                f16x2 d = max2(zq[qi][i] - tv, zero2);
                s1p = s1p + d;
                s2p = s2p + d * d;
            }
            s1a[qi] = (float)s1p.x + (float)s1p.y;
            s2a[qi] = (float)s2p.x + (float)s2p.y;
        }
#pragma unroll
        for (int off = 1; off <= 32; off <<= 1) {
            s1a[0] += __shfl_xor(s1a[0], off);
            s2a[0] += __shfl_xor(s2a[0], off);
            s1a[1] += __shfl_xor(s1a[1], off);
            s2a[1] += __shfl_xor(s2a[1], off);
        }
#pragma unroll
        for (int qi = 0; qi < 2; qi++)
            if (s1a[qi] > 1e-9f)
                tau[qi] = fminf(tau[qi] + (s2a[qi] - 1.0f) / (2.0f * s1a[qi]),
                                zmx[qi] - 1e-3f);
    }

    // Two exact closed-form support refines (f32 accumulation)
#pragma unroll 1
    for (int rf = 0; rf < 2; ++rf) {
        float kca[2], s1a[2], s2a[2];
#pragma unroll
        for (int qi = 0; qi < 2; qi++) {
            float kc = 0.f, s1 = 0.f, s2 = 0.f, tu = tau[qi];
#pragma unroll
            for (int i = 0; i < 16; i++) {
                float zlo = (float)zq[qi][i].x, zhi = (float)zq[qi][i].y;
                float dlo = zlo - tu, dhi = zhi - tu;
                if (dlo > 0.f) { kc += 1.f; s1 += dlo; s2 = fmaf(dlo, dlo, s2); }
                if (dhi > 0.f) { kc += 1.f; s1 += dhi; s2 = fmaf(dhi, dhi, s2); }
            }
            kca[qi] = kc; s1a[qi] = s1; s2a[qi] = s2;
        }
#pragma unroll
        for (int off = 1; off <= 32; off <<= 1) {
#pragma unroll
            for (int qi = 0; qi < 2; qi++) {
                kca[qi] += __shfl_xor(kca[qi], off);
                s1a[qi] += __shfl_xor(s1a[qi], off);
                s2a[qi] += __shfl_xor(s2a[qi], off);
            }
        }
#pragma unroll
        for (int qi = 0; qi < 2; qi++) {
            float K_ = fmaxf(kca[qi], 1.0f);
            float disc = fmaxf(s1a[qi] * s1a[qi] - K_ * (s2a[qi] - 1.0f), 0.f);
            tau[qi] += (s1a[qi] - sqrtf(disc)) / K_;
        }
    }

    // P = ((z - tau)_+)^2 -> f16, written back in place
#pragma unroll
    for (int qi = 0; qi < 2; qi++) {
        const int q = 2 * w + qi;
        const int base = q * 4096, sw = (q & 7) << 4;
        const float tu = tau[qi];
#pragma unroll
        for (int i = 0; i < 4; i++) {
            union { f16x8 v; f16x2 h[4]; } u;
#pragma unroll
            for (int j = 0; j < 4; j++) {
                float lo = fmaxf((float)zq[qi][i * 4 + j].x - tu, 0.f);
                float hi = fmaxf((float)zq[qi][i * 4 + j].y - tu, 0.f);
                f16x2 pp; pp.x = (f16)(lo * lo); pp.y = (f16)(hi * hi);
                u.h[j] = pp;
            }
            *(f16x8*)&LB[base + (((lane + 64 * i) << 4) ^ sw)] = u.v;
        }
    }
    __syncthreads();

    // ---- Phase 3: PV (B-frags from LDS, A-frags = Vt d-rows) ----
    f32x4 O[4];
#pragma unroll
    for (int nd = 0; nd < 4; nd++) O[nd] = vz;
#pragma unroll
    for (int t = 0; t < 16; t++) {
        const int j0 = kbase + t * 16;
        f16x4 pf = *(const f16x4*)&LB[c * 4096 + (((j0 + g * 4) * 2) ^ swc)];
#pragma unroll
        for (int nd = 0; nd < 4; nd++) {
            f16x4 va = *(const f16x4*)&Vt[(size_t)(bh * 64 + nd * 16 + c) * 2048 + j0 + g * 4];
            O[nd] = __builtin_amdgcn_mfma_f32_16x16x16f16(va, pf, O[nd], 0, 0, 0);
        }
    }
    __syncthreads();   // all P reads done; LB reused as f32 Ored

    float* Ored = (float*)LB;                        // [8][16][68] f32
#pragma unroll
    for (int nd = 0; nd < 4; nd++)
        *(f32x4*)&Ored[(w * 16 + c) * 68 + nd * 16 + g * 4] = O[nd];
    __syncthreads();

    const int qrow = tid >> 5;
    const int dp = tid & 31;
    float o0 = 0.f, o1 = 0.f;
#pragma unroll
    for (int ww = 0; ww < 8; ww++) {
        float2 v = *(const float2*)&Ored[(ww * 16 + qrow) * 68 + dp * 2];
        o0 += v.x; o1 += v.y;
    }
    f16x2 pk;
    pk.x = (f16)o0;
    pk.y = (f16)o1;
    *(f16x2*)&AO[(size_t)(b * 2048 + qb + qrow) * 1024 + h * 64 + dp * 2] = pk;
}

// ---------------------------------------------------------------------------
extern "C" void kernel_launch(void* const* d_in, const int* in_sizes, int n_in,
                              void* d_out, int out_size, void* d_ws, size_t ws_size,
                              hipStream_t stream)
{
    const float* q  = (const float*)d_in[0];
    const float* k  = (const float*)d_in[1];
    const float* v  = (const float*)d_in[2];
    const int* mask = (const int*)d_in[3];
    const float* wq = (const float*)d_in[4];
    const float* wk = (const float*)d_in[5];
    const float* wv = (const float*)d_in[6];
    const float* wo = (const float*)d_in[7];

    char* ws = (char*)d_ws;
    const size_t SZ = 8388608ull;            // 8 MB per f16 buffer
    f16* Qb  = (f16*)(ws);
    f16* Kb  = (f16*)(ws + SZ);
    f16* Vtb = (f16*)(ws + 2 * SZ);
    f16* AOb = (f16*)(ws + 3 * SZ);
    u32* Mb  = (u32*)(ws + 4 * SZ);          // 1 MB packed mask

    pack_mask<<<1024, 256, 0, stream>>>(mask, Mb);

    dim3 gg(32, 8);
    gemm_proj<0><<<gg, 512, 0, stream>>>(q, wq, Qb);
    gemm_proj<1><<<gg, 512, 0, stream>>>(k, wk, Kb);
    gemm_proj<2><<<gg, 512, 0, stream>>>(v, wv, Vtb);
    attn_entmax<<<dim3(128, 32), 512, 0, stream>>>(Qb, Kb, Vtb, Mb, AOb);
    gemm_proj<3><<<gg, 512, 0, stream>>>(AOb, wo, d_out);
}

// Round 6
// 526.561 us; speedup vs baseline: 1.0407x; 1.0407x over previous
//
#include <hip/hip_runtime.h>

// Shapes: B=2, L=2048, D_MODEL=1024, H=16, D_K=64
// Pipeline:
//  0) pack_mask: mask int32 [B][L][L] -> bit-packed u32 [B][L][L/32].
//  1) gemm_proj<0/1>: Q/K = x @ W^T (f32 in, f16 out, head-major [bh][l][64]).
//     Q pre-scaled by 1/16 = (1/sqrt(64)) * (1/2)  [entmax z = scores/2].
//  2) gemm_proj<2>: V projection, epilogue writes Vt [bh][64][l] directly.
//  3) attn_entmax: block = 16 queries x 2048 keys, 8 waves, XCD-swizzled grid.
//     Swapped QK^T -> packed f16x2 scores in regs (lane holds 64 scores of ONE query).
//     Entmax solve: 3 cross-wave Newton iters from tau0=zmax-1 (f32 sums, monotone
//     from below => tau3 <= tau*), filter survivors z > tau3-1e-3 into per-query
//     LDS buckets (true support ~10-30; worst-case ~150 < CAP=512), then per
//     half-wave: 4 Newton + 3 exact closed-form support refines on the bucket.
//     P + PV directly from registers (16x16x16 mfma, B-frag == QK D-frag layout).
//  4) gemm_proj<3>: out = AO @ Wo^T -> f32 d_out.

typedef _Float16 f16;
typedef __attribute__((ext_vector_type(8))) _Float16 f16x8;
typedef __attribute__((ext_vector_type(4))) _Float16 f16x4;
typedef __attribute__((ext_vector_type(2))) _Float16 f16x2;
typedef __attribute__((ext_vector_type(4))) float f32x4;
typedef unsigned int u32;

static __device__ __forceinline__ f16x2 max2(f16x2 a, f16x2 b) {
    f16x2 r;
    r.x = a.x > b.x ? a.x : b.x;
    r.y = a.y > b.y ? a.y : b.y;
    return r;
}

// ---------------------------------------------------------------------------
// mask [2][2048][2048] int -> bits [2][2048][64] u32
// ---------------------------------------------------------------------------
__global__ __launch_bounds__(256)
void pack_mask(const int* __restrict__ mask, u32* __restrict__ bits)
{
    int idx = blockIdx.x * 256 + threadIdx.x;        // 0..262143
    const int4* p = (const int4*)&mask[(size_t)idx * 32];
    u32 v = 0;
#pragma unroll
    for (int i = 0; i < 8; i++) {
        int4 m = p[i];
        if (m.x != 0) v |= 1u << (i * 4 + 0);
        if (m.y != 0) v |= 1u << (i * 4 + 1);
        if (m.z != 0) v |= 1u << (i * 4 + 2);
        if (m.w != 0) v |= 1u << (i * 4 + 3);
    }
    bits[idx] = v;
}

// ---------------------------------------------------------------------------
// GEMM: C[M=4096, N=1024] = A[M,1024] * W[N,K=1024]^T
// MODE 0: Q (f16, *1/16, head-major)  1: K  2: V->Vt [bh][64][l]  3: OUT f32
// ---------------------------------------------------------------------------
template <int MODE>
__global__ __launch_bounds__(512)
void gemm_proj(const void* __restrict__ Ap, const float* __restrict__ Wp,
               void* __restrict__ Cp)
{
    __shared__ __align__(16) f16 As[128 * 40];
    __shared__ __align__(16) f16 Bs[128 * 40];

    const int tid = threadIdx.x;
    const int mBase = blockIdx.x * 128;
    const int nBase = blockIdx.y * 128;

    const int lane = tid & 63, w = tid >> 6;
    const int g = lane >> 4, c = lane & 15;
    const int wm = w >> 1, wn = w & 1;

    const int sr = tid >> 2;
    const int sq = tid & 3;

    f32x4 acc[2][4];
    const f32x4 vzero = {0.f, 0.f, 0.f, 0.f};
#pragma unroll
    for (int i = 0; i < 2; i++)
#pragma unroll
        for (int j = 0; j < 4; j++) acc[i][j] = vzero;

    for (int k0 = 0; k0 < 1024; k0 += 32) {
        __syncthreads();
        {
            f16x8 av;
            if constexpr (MODE == 3) {
                const f16* A = (const f16*)Ap;
                av = *(const f16x8*)&A[(size_t)(mBase + sr) * 1024 + k0 + sq * 8];
            } else {
                const float* A = (const float*)Ap;
                const float4* p = (const float4*)&A[(size_t)(mBase + sr) * 1024 + k0 + sq * 8];
                float4 x0 = p[0], x1 = p[1];
                av[0] = (f16)x0.x; av[1] = (f16)x0.y; av[2] = (f16)x0.z; av[3] = (f16)x0.w;
                av[4] = (f16)x1.x; av[5] = (f16)x1.y; av[6] = (f16)x1.z; av[7] = (f16)x1.w;
            }
            *(f16x8*)&As[sr * 40 + sq * 8] = av;

            const float4* pw = (const float4*)&Wp[(size_t)(nBase + sr) * 1024 + k0 + sq * 8];
            float4 w0 = pw[0], w1 = pw[1];
            f16x8 bv;
            bv[0] = (f16)w0.x; bv[1] = (f16)w0.y; bv[2] = (f16)w0.z; bv[3] = (f16)w0.w;
            bv[4] = (f16)w1.x; bv[5] = (f16)w1.y; bv[6] = (f16)w1.z; bv[7] = (f16)w1.w;
            *(f16x8*)&Bs[sr * 40 + sq * 8] = bv;
        }
        __syncthreads();

        f16x8 af[2], bf[4];
#pragma unroll
        for (int mt = 0; mt < 2; mt++)
            af[mt] = *(const f16x8*)&As[(wm * 32 + mt * 16 + c) * 40 + g * 8];
#pragma unroll
        for (int nt = 0; nt < 4; nt++)
            bf[nt] = *(const f16x8*)&Bs[(wn * 64 + nt * 16 + c) * 40 + g * 8];
#pragma unroll
        for (int mt = 0; mt < 2; mt++)
#pragma unroll
            for (int nt = 0; nt < 4; nt++)
                acc[mt][nt] = __builtin_amdgcn_mfma_f32_16x16x32_f16(af[mt], bf[nt], acc[mt][nt], 0, 0, 0);
    }

#pragma unroll
    for (int mt = 0; mt < 2; mt++)
#pragma unroll
        for (int nt = 0; nt < 4; nt++) {
            int row0 = mBase + wm * 32 + mt * 16 + g * 4;
            int col = nBase + wn * 64 + nt * 16 + c;
            if constexpr (MODE == 3) {
#pragma unroll
                for (int r = 0; r < 4; r++)
                    ((float*)Cp)[(size_t)(row0 + r) * 1024 + col] = acc[mt][nt][r];
            } else if constexpr (MODE == 2) {
                int b = row0 >> 11, l0 = row0 & 2047;
                int h = col >> 6, dk = col & 63;
                f16x4 pv;
#pragma unroll
                for (int r = 0; r < 4; r++) pv[r] = (f16)acc[mt][nt][r];
                *(f16x4*)&((f16*)Cp)[((size_t)(b * 16 + h) * 64 + dk) * 2048 + l0] = pv;
            } else {
#pragma unroll
                for (int r = 0; r < 4; r++) {
                    int row = row0 + r;
                    float v = acc[mt][nt][r];
                    if constexpr (MODE == 0) v *= 0.0625f;
                    int b = row >> 11, l = row & 2047;
                    int h = col >> 6, dk = col & 63;
                    ((f16*)Cp)[((size_t)(b * 16 + h) * 2048 + l) * 64 + dk] = (f16)v;
                }
            }
        }
}

// ---------------------------------------------------------------------------
// Attention + exact 1.5-entmax via Newton-tightened survivor filtering.
// ---------------------------------------------------------------------------
__global__ __launch_bounds__(512, 4)
void attn_entmax(const f16* __restrict__ Q, const f16* __restrict__ Kh,
                 const f16* __restrict__ Vt, const u32* __restrict__ mbits,
                 f16* __restrict__ AO)
{
    constexpr int CAP = 512;
    // Overlay: bucket[16][512] f32 (32 KB) lives before the taus barrier;
    // Ored [8][16][68] f32 (34.8 KB) lives after it.
    __shared__ __align__(16) char LB[8 * 16 * 68 * 4];
    __shared__ int cntS[16];
    __shared__ float redM[8][16];
    __shared__ float redN[2][8][16][2];
    __shared__ float taus[16];

    float (*bucket)[CAP] = (float (*)[CAP])LB;
    float* Ored = (float*)LB;

    const int tid = threadIdx.x;
    const int w = tid >> 6, lane = tid & 63;
    const int g = lane >> 4, c = lane & 15;

    // XCD-aware swizzle: same bh stays on one XCD (Q/K/V slice ~3MB < 4MB L2)
    const int bid = blockIdx.x;
    const int q8 = bid >> 3;
    const int bh = (bid & 7) * 4 + (q8 >> 7);
    const int qb = (q8 & 127) * 16;
    const int b = bh >> 4, h = bh & 15;
    const int kbase = w * 256;

    if (tid < 16) cntS[tid] = 0;

    // ---- Q B-fragments (col = query = c, k-dim = d) ----
    const f16* qp = &Q[(size_t)(bh * 2048 + qb + c) * 64 + g * 8];
    f16x8 bq0 = *(const f16x8*)qp;
    f16x8 bq1 = *(const f16x8*)(qp + 32);

    const uint4* mp = (const uint4*)&mbits[(size_t)(b * 2048 + qb + c) * 64 + w * 8];
    uint4 mA = mp[0], mB = mp[1];
    u32 mb[8] = {mA.x, mA.y, mA.z, mA.w, mB.x, mB.y, mB.z, mB.w};

    // ---- scores S^T -> mask -> packed f16x2 hS[32] (keys t*16+g*4+{0..3}) ----
    f16x2 hS[32];
    const f32x4 vz = {0.f, 0.f, 0.f, 0.f};
#pragma unroll
    for (int t = 0; t < 16; t++) {
        const f16* kp = &Kh[(size_t)(bh * 2048 + kbase + t * 16 + c) * 64 + g * 8];
        f16x8 ka0 = *(const f16x8*)kp;
        f16x8 ka1 = *(const f16x8*)(kp + 32);
        f32x4 z = __builtin_amdgcn_mfma_f32_16x16x32_f16(ka0, bq0, vz, 0, 0, 0);
        z = __builtin_amdgcn_mfma_f32_16x16x32_f16(ka1, bq1, z, 0, 0, 0);
        u32 b4 = mb[t >> 1] >> ((t & 1) * 16 + g * 4);
#pragma unroll
        for (int r = 0; r < 4; r++)
            if (!((b4 >> r) & 1)) z[r] = -30000.f;
        f16x2 p0, p1;
        p0.x = (f16)z[0]; p0.y = (f16)z[1];
        p1.x = (f16)z[2]; p1.y = (f16)z[3];
        hS[2 * t] = p0;
        hS[2 * t + 1] = p1;
    }

    // ---- zmax per query (wave partial -> cross-wave via redM) ----
    f16x2 m2 = hS[0];
#pragma unroll
    for (int i = 1; i < 32; i++) m2 = max2(m2, hS[i]);
    float zx = fmaxf((float)m2.x, (float)m2.y);
    zx = fmaxf(zx, __shfl_xor(zx, 16));
    zx = fmaxf(zx, __shfl_xor(zx, 32));
    if (lane < 16) redM[w][c] = zx;
    __syncthreads();
    float zmax = -3e38f;
#pragma unroll
    for (int ww = 0; ww < 8; ww++) zmax = fmaxf(zmax, redM[ww][c]);

    // ---- 3 cross-wave Newton iters from below (f32 sums) -> tau3 <= tau* ----
    float tau = zmax - 1.0f;
    int buf = 0;
#pragma unroll 1
    for (int it = 0; it < 3; ++it) {
        float s1 = 0.f, s2 = 0.f;
#pragma unroll
        for (int i = 0; i < 32; i++) {
            float lo = fmaxf((float)hS[i].x - tau, 0.f);
            float hi = fmaxf((float)hS[i].y - tau, 0.f);
            s1 += lo + hi;
            s2 = fmaf(lo, lo, fmaf(hi, hi, s2));
        }
        s1 += __shfl_xor(s1, 16); s1 += __shfl_xor(s1, 32);
        s2 += __shfl_xor(s2, 16); s2 += __shfl_xor(s2, 32);
        if (lane < 16) { redN[buf][w][c][0] = s1; redN[buf][w][c][1] = s2; }
        __syncthreads();
        float a = 0.f, f = 0.f;
#pragma unroll
        for (int ww = 0; ww < 8; ww++) {
            float2 v = *(const float2*)&redN[buf][ww][c][0];
            a += v.x; f += v.y;
        }
        if (a > 1e-12f)
            tau = fminf(tau + (f - 1.0f) / (2.0f * a), zmax - 1e-3f);
        buf ^= 1;
    }

    // ---- filter survivors (z > tau3 - eps ⊇ true support) into buckets ----
    const float thr = tau - 1e-3f;
#pragma unroll
    for (int i = 0; i < 32; i++) {
        float lo = (float)hS[i].x, hi = (float)hS[i].y;
        if (lo > thr) {
            int id = atomicAdd(&cntS[c], 1);
            if (id < CAP) bucket[c][id] = lo;
        }
        if (hi > thr) {
            int id = atomicAdd(&cntS[c], 1);
            if (id < CAP) bucket[c][id] = hi;
        }
    }
    __syncthreads();

    // ---- solve: wave w -> query 2w (lanes 0-31) and 2w+1 (lanes 32-63) ----
    const int half = lane >> 5, sl = lane & 31;
    const int q = 2 * w + half;
    const int cnt = min(cntS[q], CAP);
    const int ns = (cnt + 31) >> 5;
    float zq = -3e38f;
#pragma unroll
    for (int ww = 0; ww < 8; ww++) zq = fmaxf(zq, redM[ww][q]);
    float tq = __shfl(tau, (q & 15) + (half ? 32 : 0));  // start from global tau3 of query q

#pragma unroll 1
    for (int it = 0; it < 4; ++it) {
        float s1 = 0.f, s2 = 0.f;
#pragma unroll 1
        for (int s = 0; s < ns; s++) {
            int i = sl + 32 * s;
            float v = (i < cnt) ? bucket[q][i] : -1e30f;
            float d = fmaxf(v - tq, 0.f);
            s1 += d;
            s2 = fmaf(d, d, s2);
        }
#pragma unroll
        for (int off = 1; off <= 16; off <<= 1) {
            s1 += __shfl_xor(s1, off);
            s2 += __shfl_xor(s2, off);
        }
        if (s1 > 1e-12f)
            tq = fminf(tq + (s2 - 1.0f) / (2.0f * s1), zq - 1e-3f);
    }
#pragma unroll 1
    for (int rf = 0; rf < 3; ++rf) {
        float kc = 0.f, s1 = 0.f, s2 = 0.f;
#pragma unroll 1
        for (int s = 0; s < ns; s++) {
            int i = sl + 32 * s;
            float v = (i < cnt) ? bucket[q][i] : -1e30f;
            float d = v - tq;
            if (d > 0.f) { kc += 1.f; s1 += d; s2 = fmaf(d, d, s2); }
        }
#pragma unroll
        for (int off = 1; off <= 16; off <<= 1) {
            kc += __shfl_xor(kc, off);
            s1 += __shfl_xor(s1, off);
            s2 += __shfl_xor(s2, off);
        }
        float K_ = fmaxf(kc, 1.0f);
        float disc = fmaxf(s1 * s1 - K_ * (s2 - 1.0f), 0.f);
        tq += (s1 - sqrtf(disc)) / K_;
    }
    if (sl == 0) taus[q] = tq;
    __syncthreads();                 // taus ready; bucket dead -> LB becomes Ored

    // ---- P = ((z - tau)_+)^2 -> PV directly from regs (16x16x16) ----
    const float tc = taus[c];
    f32x4 O[4];
#pragma unroll
    for (int nd = 0; nd < 4; nd++) O[nd] = vz;
#pragma unroll
    for (int t = 0; t < 16; t++) {
        f16x4 pf;
        float d0 = fmaxf((float)hS[2 * t].x - tc, 0.f);
        float d1 = fmaxf((float)hS[2 * t].y - tc, 0.f);
        float d2 = fmaxf((float)hS[2 * t + 1].x - tc, 0.f);
        float d3 = fmaxf((float)hS[2 * t + 1].y - tc, 0.f);
        pf[0] = (f16)(d0 * d0);
        pf[1] = (f16)(d1 * d1);
        pf[2] = (f16)(d2 * d2);
        pf[3] = (f16)(d3 * d3);
        const int j0 = kbase + t * 16;
#pragma unroll
        for (int nd = 0; nd < 4; nd++) {
            f16x4 va = *(const f16x4*)&Vt[(size_t)(bh * 64 + nd * 16 + c) * 2048 + j0 + g * 4];
            O[nd] = __builtin_amdgcn_mfma_f32_16x16x16f16(va, pf, O[nd], 0, 0, 0);
        }
    }

    // ---- cross-wave O reduction (Ored overlays bucket) ----
#pragma unroll
    for (int nd = 0; nd < 4; nd++)
        *(f32x4*)&Ored[(w * 16 + c) * 68 + nd * 16 + g * 4] = O[nd];
    __syncthreads();

    const int qrow = tid >> 5;
    const int dp = tid & 31;
    float o0 = 0.f, o1 = 0.f;
#pragma unroll
    for (int ww = 0; ww < 8; ww++) {
        float2 v = *(const float2*)&Ored[(ww * 16 + qrow) * 68 + dp * 2];
        o0 += v.x; o1 += v.y;
    }
    f16x2 pk;
    pk.x = (f16)o0;
    pk.y = (f16)o1;
    *(f16x2*)&AO[(size_t)(b * 2048 + qb + qrow) * 1024 + h * 64 + dp * 2] = pk;
}

// ---------------------------------------------------------------------------
extern "C" void kernel_launch(void* const* d_in, const int* in_sizes, int n_in,
                              void* d_out, int out_size, void* d_ws, size_t ws_size,
                              hipStream_t stream)
{
    const float* q  = (const float*)d_in[0];
    const float* k  = (const float*)d_in[1];
    const float* v  = (const float*)d_in[2];
    const int* mask = (const int*)d_in[3];
    const float* wq = (const float*)d_in[4];
    const float* wk = (const float*)d_in[5];
    const float* wv = (const float*)d_in[6];
    const float* wo = (const float*)d_in[7];

    char* ws = (char*)d_ws;
    const size_t SZ = 8388608ull;            // 8 MB per f16 buffer
    f16* Qb  = (f16*)(ws);
    f16* Kb  = (f16*)(ws + SZ);
    f16* Vtb = (f16*)(ws + 2 * SZ);
    f16* AOb = (f16*)(ws + 3 * SZ);
    u32* Mb  = (u32*)(ws + 4 * SZ);          // 1 MB packed mask

    pack_mask<<<1024, 256, 0, stream>>>(mask, Mb);

    dim3 gg(32, 8);
    gemm_proj<0><<<gg, 512, 0, stream>>>(q, wq, Qb);
    gemm_proj<1><<<gg, 512, 0, stream>>>(k, wk, Kb);
    gemm_proj<2><<<gg, 512, 0, stream>>>(v, wv, Vtb);
    attn_entmax<<<4096, 512, 0, stream>>>(Qb, Kb, Vtb, Mb, AOb);
    gemm_proj<3><<<gg, 512, 0, stream>>>(AOb, wo, d_out);
}